// Round 12
// baseline (612.598 us; speedup 1.0000x reference)
//
#include <hip/hip_runtime.h>
#include <hip/hip_bf16.h>
#include <cstdint>
#include <cstddef>

static inline size_t align_up(size_t x, size_t a) { return (x + a - 1) & ~(a - 1); }

typedef __attribute__((ext_vector_type(4))) float f32x4;
typedef __attribute__((ext_vector_type(4))) unsigned int u32x4;
typedef __attribute__((ext_vector_type(2))) unsigned int u32x2;
typedef __attribute__((ext_vector_type(8))) short bf16x8;

__device__ inline float bf2f(unsigned int u16) {        // low 16 bits hold bf16
    return __uint_as_float(u16 << 16);
}
__device__ inline float bflo(unsigned int v) { return __uint_as_float(v << 16); }
__device__ inline float bfhi(unsigned int v) { return __uint_as_float(v & 0xffff0000u); }
__device__ inline unsigned short f2bf(float f) {        // round-to-nearest-even
    unsigned int u = __float_as_uint(f);
    u = (u + 0x7fffu + ((u >> 16) & 1u)) >> 16;
    return (unsigned short)u;
}

// Bijective XCD-chunk swizzle (m204): blockIdx round-robins xcd = id%8; give
// each XCD a CONTIGUOUS wgid chunk so consecutive blocks on one XCD share
// operand panels in its private L2.
__device__ inline int xcd_swizzle(int id, int nwg) {
    int q = nwg >> 3, r8 = nwg & 7;
    int xcd = id & 7, pos = id >> 3;
    int base = (xcd < r8) ? xcd * (q + 1) : r8 * (q + 1) + (xcd - r8) * q;
    return base + pos;
}

#define GLD_LDS(gp, lp) \
    __builtin_amdgcn_global_load_lds( \
        (const __attribute__((address_space(1))) unsigned int*)(gp), \
        (__attribute__((address_space(3))) unsigned int*)(lp), 16, 0, 0)

// ---------------------------------------------------------------------------
__global__ void zero_kernel(int* __restrict__ p, int n) {
    int i = blockIdx.x * 256 + threadIdx.x;
    if (i < n) p[i] = 0;
}

// Edge-encoding detection, single block, sampled, no atomics.
__global__ void detect_kernel(const int* __restrict__ e, int* __restrict__ nz, int E) {
    int t = threadIdx.x;  // 0..255, one block
    long long stride = (long long)E / 4096;
    if (stride < 1) stride = 1;
    int any = 0;
    for (int k = 0; k < 16; ++k) {
        long long idx = (long long)(t * 16 + k) * stride;
        if (idx < E && e[2 * idx + 1] != 0) any = 1;
    }
    if (any) nz[0] = 1;  // same-value race is benign
}

__global__ void conv_count_kernel(const int* __restrict__ eraw, const int* __restrict__ nz,
                                  int* __restrict__ src32, int* __restrict__ dst32,
                                  int* __restrict__ cnt, int E) {
    int i = blockIdx.x * blockDim.x + threadIdx.x;
    if (i >= E) return;
    int s, d;
    if (*nz == 0) {  // int64 storage
        const long long* e64 = (const long long*)eraw;
        s = (int)e64[i];
        d = (int)e64[i + E];
    } else {         // int32 storage
        s = eraw[i];
        d = eraw[i + E];
    }
    src32[i] = s;
    dst32[i] = d;
    atomicAdd(&cnt[d], 1);
}

// 3-kernel exclusive scan over cnt[0..n) -> offs[0..n]
__global__ void scan1_kernel(const int* __restrict__ cnt, int* __restrict__ partial,
                             int n, int C) {
    int t = blockIdx.x * 256 + threadIdx.x;  // 0..1023
    int s = 0;
    int base = t * C;
    for (int i = 0; i < C; ++i) {
        int idx = base + i;
        if (idx < n) s += cnt[idx];
    }
    partial[t] = s;
}

__global__ void __launch_bounds__(1024) scan2_kernel(int* __restrict__ partial) {
    __shared__ int sh[1024];
    int t = threadIdx.x;
    sh[t] = partial[t];
    __syncthreads();
    for (int off = 1; off < 1024; off <<= 1) {
        int v = (t >= off) ? sh[t - off] : 0;
        __syncthreads();
        sh[t] += v;
        __syncthreads();
    }
    partial[t] = (t == 0) ? 0 : sh[t - 1];  // exclusive
}

__global__ void scan3_kernel(const int* __restrict__ cnt, const int* __restrict__ partial,
                             int* __restrict__ offs, int n, int C, int E) {
    int t = blockIdx.x * 256 + threadIdx.x;
    int run = partial[t];
    int base = t * C;
    for (int i = 0; i < C; ++i) {
        int idx = base + i;
        if (idx < n) {
            offs[idx] = run;
            run += cnt[idx];
        }
    }
    if (t == 0) offs[n] = E;
}

__global__ void inv_kernel(const int* __restrict__ cnt, float* __restrict__ inv, int n) {
    int i = blockIdx.x * 256 + threadIdx.x;
    if (i < n) inv[i] = 1.0f / (float)max(cnt[i], 1);
}

__global__ void fill_kernel(const int* __restrict__ src32, const int* __restrict__ dst32,
                            const int* __restrict__ offs, int* __restrict__ cursor,
                            int* __restrict__ sorted, int E) {
    int i = blockIdx.x * 256 + threadIdx.x;
    if (i >= E) return;
    int d = dst32[i];
    int p = offs[d] + atomicAdd(&cursor[d], 1);
    sorted[p] = src32[i];
}

// fp32 -> bf16, vectorized x4
__global__ void cvt_bf16_kernel(const float* __restrict__ x, unsigned short* __restrict__ xb,
                                int n4) {
    int i = blockIdx.x * 256 + threadIdx.x;
    if (i >= n4) return;
    float4 v = *(const float4*)(x + (size_t)i * 4);
    uint2 o;
    o.x = (unsigned int)f2bf(v.x) | ((unsigned int)f2bf(v.y) << 16);
    o.y = (unsigned int)f2bf(v.z) | ((unsigned int)f2bf(v.w) << 16);
    *(uint2*)(xb + (size_t)i * 4) = o;
}

// ---------------------------------------------------------------------------
// Aggregation kernels (unchanged from round-11 best).
// Regime: gathers throughput-bound on the beyond-L2 fetch path (~3.3-3.8
// TB/s); dur tracks FETCH bytes; hit rate is temporal. Layer-1 P half-split
// [2][Mpad][256], two sequential launches. Binary 4/2/1 tails; single-use
// streams (Q, out) non-temporal.
// ---------------------------------------------------------------------------
__global__ void __launch_bounds__(256) agg128_kernel(
    const unsigned short* __restrict__ X, const int* __restrict__ srt,
    const int* __restrict__ offs, const float* __restrict__ invc,
    unsigned short* __restrict__ out, int nNodes) {
    int node = blockIdx.x * 4 + (threadIdx.x >> 6);
    if (node >= nNodes) return;
    int lane = threadIdx.x & 63;
    const unsigned short* xp = X + (size_t)lane * 2;
    int beg = offs[node], end = offs[node + 1];
    float sc = invc[node];
    float a0 = 0.f, a1 = 0.f;
    int e = beg;
    for (; e + 8 <= end; e += 8) {
        unsigned int v[8];
#pragma unroll
        for (int u = 0; u < 8; ++u)
            v[u] = *(const unsigned int*)(xp + (size_t)srt[e + u] * 128);
#pragma unroll
        for (int u = 0; u < 8; ++u) {
            a0 += bflo(v[u]);
            a1 += bfhi(v[u]);
        }
    }
    int r = end - e;
    if (r & 4) {
        unsigned int v[4];
#pragma unroll
        for (int u = 0; u < 4; ++u)
            v[u] = *(const unsigned int*)(xp + (size_t)srt[e + u] * 128);
#pragma unroll
        for (int u = 0; u < 4; ++u) { a0 += bflo(v[u]); a1 += bfhi(v[u]); }
        e += 4;
    }
    if (r & 2) {
        unsigned int v[2];
#pragma unroll
        for (int u = 0; u < 2; ++u)
            v[u] = *(const unsigned int*)(xp + (size_t)srt[e + u] * 128);
#pragma unroll
        for (int u = 0; u < 2; ++u) { a0 += bflo(v[u]); a1 += bfhi(v[u]); }
        e += 2;
    }
    if (r & 1) {
        unsigned int v = *(const unsigned int*)(xp + (size_t)srt[e] * 128);
        a0 += bflo(v);
        a1 += bfhi(v);
    }
    unsigned int o = (unsigned int)f2bf(a0 * sc) | ((unsigned int)f2bf(a1 * sc) << 16);
    __builtin_nontemporal_store(o, (unsigned int*)(out + (size_t)node * 128 + lane * 2));
}

// Layer-1 fused aggregation, HALF-SPLIT: out[dst][h*256+..] =
// relu(inv*sum Ph[src] + Q[dst][h*256+..]). P: [2][Mpad][256] bf16.
__global__ void __launch_bounds__(256) aggfuse512h_kernel(
    const unsigned short* __restrict__ P, const unsigned short* __restrict__ Q,
    const int* __restrict__ srt, const int* __restrict__ offs,
    const float* __restrict__ invc, unsigned short* __restrict__ out,
    int nNodes, int Mpad, int half) {
    int node = blockIdx.x * 4 + (threadIdx.x >> 6);
    if (node >= nNodes) return;
    int lane = threadIdx.x & 63;
    const unsigned short* pp = P + (size_t)half * Mpad * 256 + lane * 4;
    int beg = offs[node], end = offs[node + 1];
    float sc = invc[node];
    float a0 = 0.f, a1 = 0.f, a2 = 0.f, a3 = 0.f;
#define ACC4(v)                              \
    do {                                     \
        a0 += bflo((v).x);                   \
        a1 += bfhi((v).x);                   \
        a2 += bflo((v).y);                   \
        a3 += bfhi((v).y);                   \
    } while (0)
    int e = beg;
    for (; e + 8 <= end; e += 8) {
        uint2 v[8];
#pragma unroll
        for (int u = 0; u < 8; ++u)
            v[u] = *(const uint2*)(pp + (size_t)srt[e + u] * 256);
#pragma unroll
        for (int u = 0; u < 8; ++u) ACC4(v[u]);
    }
    int r = end - e;
    if (r & 4) {
        uint2 v[4];
#pragma unroll
        for (int u = 0; u < 4; ++u)
            v[u] = *(const uint2*)(pp + (size_t)srt[e + u] * 256);
#pragma unroll
        for (int u = 0; u < 4; ++u) ACC4(v[u]);
        e += 4;
    }
    if (r & 2) {
        uint2 v[2];
#pragma unroll
        for (int u = 0; u < 2; ++u)
            v[u] = *(const uint2*)(pp + (size_t)srt[e + u] * 256);
#pragma unroll
        for (int u = 0; u < 2; ++u) ACC4(v[u]);
        e += 2;
    }
    if (r & 1) {
        uint2 v = *(const uint2*)(pp + (size_t)srt[e] * 256);
        ACC4(v);
    }
#undef ACC4
    size_t qo = (size_t)node * 512 + half * 256 + lane * 4;
    u32x2 q = __builtin_nontemporal_load((const u32x2*)(Q + qo));
    float r0 = fmaxf(a0 * sc + bflo(q.x), 0.f);
    float r1 = fmaxf(a1 * sc + bfhi(q.x), 0.f);
    float r2 = fmaxf(a2 * sc + bflo(q.y), 0.f);
    float r3 = fmaxf(a3 * sc + bfhi(q.y), 0.f);
    u32x2 o;
    o.x = (unsigned int)f2bf(r0) | ((unsigned int)f2bf(r1) << 16);
    o.y = (unsigned int)f2bf(r2) | ((unsigned int)f2bf(r3) << 16);
    __builtin_nontemporal_store(o, (u32x2*)(out + qo));
}

// D=256 variant, fp32 Q and fp32 out (final layer, no relu).
__global__ void __launch_bounds__(256) aggfuse256_kernel(
    const unsigned short* __restrict__ P, const float* __restrict__ Q,
    const int* __restrict__ srt, const int* __restrict__ offs,
    const float* __restrict__ invc, float* __restrict__ out, int nNodes) {
    int node = blockIdx.x * 4 + (threadIdx.x >> 6);
    if (node >= nNodes) return;
    int lane = threadIdx.x & 63;
    const unsigned short* pp = P + (size_t)lane * 4;
    int beg = offs[node], end = offs[node + 1];
    float sc = invc[node];
    float a0 = 0.f, a1 = 0.f, a2 = 0.f, a3 = 0.f;
#define ACC4(v)                              \
    do {                                     \
        a0 += bflo((v).x);                   \
        a1 += bfhi((v).x);                   \
        a2 += bflo((v).y);                   \
        a3 += bfhi((v).y);                   \
    } while (0)
    int e = beg;
    for (; e + 8 <= end; e += 8) {
        uint2 v[8];
#pragma unroll
        for (int u = 0; u < 8; ++u)
            v[u] = *(const uint2*)(pp + (size_t)srt[e + u] * 256);
#pragma unroll
        for (int u = 0; u < 8; ++u) ACC4(v[u]);
    }
    int r = end - e;
    if (r & 4) {
        uint2 v[4];
#pragma unroll
        for (int u = 0; u < 4; ++u)
            v[u] = *(const uint2*)(pp + (size_t)srt[e + u] * 256);
#pragma unroll
        for (int u = 0; u < 4; ++u) ACC4(v[u]);
        e += 4;
    }
    if (r & 2) {
        uint2 v[2];
#pragma unroll
        for (int u = 0; u < 2; ++u)
            v[u] = *(const uint2*)(pp + (size_t)srt[e + u] * 256);
#pragma unroll
        for (int u = 0; u < 2; ++u) ACC4(v[u]);
        e += 2;
    }
    if (r & 1) {
        uint2 v = *(const uint2*)(pp + (size_t)srt[e] * 256);
        ACC4(v);
    }
#undef ACC4
    f32x4 q = __builtin_nontemporal_load(
        (const f32x4*)(Q + (size_t)node * 256 + lane * 4));
    f32x4 rr;
    rr.x = a0 * sc + q.x;
    rr.y = a1 * sc + q.y;
    rr.z = a2 * sc + q.z;
    rr.w = a3 * sc + q.w;
    __builtin_nontemporal_store(rr, (f32x4*)(out + (size_t)node * 256 + lane * 4));
}

// ---------------------------------------------------------------------------
// Coalesced bf16 epilogue. permM == 0: row-major [m][N]. permM != 0: half-
// split [n>>8][permM rows][256].
// ---------------------------------------------------------------------------
__device__ __forceinline__ void epilogue_bf16(
    f32x4 (&acc)[4][8], const float* bvj, int relu, int permM,
    unsigned short* smem, int wave, int lane,
    unsigned short* Cout, int m0, int n0, int wm, int wn, int M, int N) {
    unsigned short* stg = smem + wave * 2304;  // 128 cols * 18 shorts
    const int colc = lane & 15;
    const int rgrp = (lane >> 4) * 4;
    for (int i = 0; i < 4; ++i) {
        __syncthreads();
#pragma unroll
        for (int j = 0; j < 8; ++j) {
            float v0 = acc[i][j][0] + bvj[j];
            float v1 = acc[i][j][1] + bvj[j];
            float v2 = acc[i][j][2] + bvj[j];
            float v3 = acc[i][j][3] + bvj[j];
            if (relu) {
                v0 = fmaxf(v0, 0.f); v1 = fmaxf(v1, 0.f);
                v2 = fmaxf(v2, 0.f); v3 = fmaxf(v3, 0.f);
            }
            int c = j * 16 + colc;
            *(unsigned int*)&stg[c * 18 + rgrp] =
                (unsigned int)f2bf(v0) | ((unsigned int)f2bf(v1) << 16);
            *(unsigned int*)&stg[c * 18 + rgrp + 2] =
                (unsigned int)f2bf(v2) | ((unsigned int)f2bf(v3) << 16);
        }
        __syncthreads();
#pragma unroll
        for (int p = 0; p < 2; ++p) {
            int colg = lane & 15;                  // 8-col group
            int rp = p * 4 + (lane >> 4);          // row pair 0..7
            unsigned int w[8];
#pragma unroll
            for (int t = 0; t < 8; ++t)
                w[t] = *(const unsigned int*)&stg[(colg * 8 + t) * 18 + rp * 2];
            uint4 lo, hi;
            lo.x = (w[0] & 0xffffu) | (w[1] << 16);
            lo.y = (w[2] & 0xffffu) | (w[3] << 16);
            lo.z = (w[4] & 0xffffu) | (w[5] << 16);
            lo.w = (w[6] & 0xffffu) | (w[7] << 16);
            hi.x = (w[0] >> 16) | (w[1] & 0xffff0000u);
            hi.y = (w[2] >> 16) | (w[3] & 0xffff0000u);
            hi.z = (w[4] >> 16) | (w[5] & 0xffff0000u);
            hi.w = (w[6] >> 16) | (w[7] & 0xffff0000u);
            int mlo = m0 + wm * 64 + i * 16 + rp * 2;
            int n = n0 + wn * 128 + colg * 8;
            if (permM) {
                size_t base = (size_t)(n >> 8) * ((size_t)permM * 256) +
                              (size_t)mlo * 256 + (n & 255);
                if (mlo < M)     *(uint4*)&Cout[base] = lo;
                if (mlo + 1 < M) *(uint4*)&Cout[base + 256] = hi;
            } else {
                if (mlo < M)     *(uint4*)&Cout[(size_t)mlo * N + n] = lo;
                if (mlo + 1 < M) *(uint4*)&Cout[(size_t)(mlo + 1) * N + n] = hi;
            }
        }
    }
}

// ---------------------------------------------------------------------------
// MFMA SAGE GEMM (layer 0): C = relu( Aagg @ Wl^T + Aself @ Wr^T + bias )
// Round-9 dbuf pipeline + round-10 XCD swizzle + round-11 LDS k-chunk XOR
// swizzle (kept here: r11 A/B showed the swizzle's net gain lives in the
// smaller GEMMs; it REGRESSED only the big dual-L1 launch, whose 16 B-granule
// global permutation fragments TA requests — see dual_gemm swz param).
// ---------------------------------------------------------------------------
__global__ void __launch_bounds__(256, 2) sage_gemm_mfma(
    const unsigned short* __restrict__ Aagg, const unsigned short* __restrict__ Aself,
    const unsigned short* __restrict__ Wlb, const unsigned short* __restrict__ Wrb,
    const float* __restrict__ bias, unsigned short* __restrict__ Cout,
    int M, int N, int K) {
    __shared__ __attribute__((aligned(16))) unsigned short smem[24576];  // 48 KB, 2 bufs
    const int tid = threadIdx.x;
    const int lane = tid & 63;
    const int wave = tid >> 6;
    const int wm = wave >> 1, wn = wave & 1;
    const int xB = N / 256;
    const int wgid = xcd_swizzle(blockIdx.x, gridDim.x);
    const int m0 = (wgid / xB) * 128, n0 = (wgid % xB) * 256;

    f32x4 acc[4][8];
#pragma unroll
    for (int i = 0; i < 4; ++i)
#pragma unroll
        for (int j = 0; j < 8; ++j) acc[i][j] = (f32x4){0.f, 0.f, 0.f, 0.f};

    const int srow = wave * 16 + (lane >> 2);
    const int kE = ((lane & 3) ^ ((lane >> 3) & 3)) * 8;   // stage swizzle
    const int frow = lane & 15;
    const int kk = (((lane >> 4) ^ ((lane >> 1) & 3)) & 3) * 8;  // read swizzle

    const int kSteps = K / 32;          // per pass
    const int steps = kSteps * 2;       // two passes (agg, self)

    auto stage = [&](int buf, int t) {
        const unsigned short* A = (t >= kSteps) ? Aself : Aagg;
        const unsigned short* W = (t >= kSteps) ? Wrb : Wlb;
        int k0 = (t >= kSteps ? t - kSteps : t) * 32;
        unsigned short* As = smem + buf * 12288;
        unsigned short* Bs = As + 4096;
        GLD_LDS(A + (size_t)(m0 + 0 * 64 + srow) * K + k0 + kE, &As[0 * 2048 + wave * 512]);
        GLD_LDS(A + (size_t)(m0 + 1 * 64 + srow) * K + k0 + kE, &As[1 * 2048 + wave * 512]);
        GLD_LDS(W + (size_t)(n0 + 0 * 64 + srow) * K + k0 + kE, &Bs[0 * 2048 + wave * 512]);
        GLD_LDS(W + (size_t)(n0 + 1 * 64 + srow) * K + k0 + kE, &Bs[1 * 2048 + wave * 512]);
        GLD_LDS(W + (size_t)(n0 + 2 * 64 + srow) * K + k0 + kE, &Bs[2 * 2048 + wave * 512]);
        GLD_LDS(W + (size_t)(n0 + 3 * 64 + srow) * K + k0 + kE, &Bs[3 * 2048 + wave * 512]);
    };

    stage(0, 0);
    __syncthreads();
    int cur = 0;
    for (int t = 0; t < steps; ++t) {
        if (t + 1 < steps) stage(cur ^ 1, t + 1);
        unsigned short* As = smem + cur * 12288;
        unsigned short* Bs = As + 4096;
        bf16x8 af[4], bfr[8];
#pragma unroll
        for (int u = 0; u < 4; ++u)
            af[u] = *(const bf16x8*)&As[(wm * 64 + u * 16 + frow) * 32 + kk];
#pragma unroll
        for (int u = 0; u < 8; ++u)
            bfr[u] = *(const bf16x8*)&Bs[(wn * 128 + u * 16 + frow) * 32 + kk];
#pragma unroll
        for (int i = 0; i < 4; ++i)
#pragma unroll
            for (int j = 0; j < 8; ++j)
                acc[i][j] = __builtin_amdgcn_mfma_f32_16x16x32_bf16(
                    af[i], bfr[j], acc[i][j], 0, 0, 0);
        __syncthreads();
        cur ^= 1;
    }

    float bvj[8];
#pragma unroll
    for (int j = 0; j < 8; ++j) bvj[j] = bias[n0 + wn * 128 + j * 16 + (lane & 15)];
    epilogue_bf16(acc, bvj, 1, 0, smem, wave, lane, Cout, m0, n0, wm, wn, M, N);
}

// ---------------------------------------------------------------------------
// Dual-output MFMA GEMM (layers 1-2): P = A@Wl^T ; Q = A@Wr^T + bias.
// Round-12: swz selects the LDS k-chunk XOR swizzle at RUNTIME (loop-
// invariant init math; avoids template codegen perturbation). r10/r11 A/B:
// the swizzle fixed K-loop bank conflicts (8.0M->3.2M) but its 16 B-granule
// global permutation fragments TA coalescing and REGRESSED the big layer-1
// launch (83->100 us) while helping the smaller launches. So: swz=0 for
// layer-1 (plain contiguous staging), swz=1 for layer-2.
// ---------------------------------------------------------------------------
__global__ void __launch_bounds__(256, 2) dual_gemm_mfma(
    const unsigned short* __restrict__ A,
    const unsigned short* __restrict__ Wlb, const unsigned short* __restrict__ Wrb,
    const float* __restrict__ bias, unsigned short* __restrict__ P,
    void* __restrict__ Q, int M, int N, int K, int q_fp32, int permM, int swz) {
    __shared__ __attribute__((aligned(16))) unsigned short smem[24576];  // 48 KB, 2 bufs
    const int tid = threadIdx.x;
    const int lane = tid & 63;
    const int wave = tid >> 6;
    const int wm = wave >> 1, wn = wave & 1;
    const int xB = 2 * N / 256;
    const int wgid = xcd_swizzle(blockIdx.x, gridDim.x);
    const int m0 = (wgid / xB) * 128;
    const int n0s = (wgid % xB) * 256;         // in [0, 2N)
    const int isQ = n0s >= N;
    const int n0 = isQ ? n0s - N : n0s;
    const unsigned short* W = isQ ? Wrb : Wlb;

    f32x4 acc[4][8];
#pragma unroll
    for (int i = 0; i < 4; ++i)
#pragma unroll
        for (int j = 0; j < 8; ++j) acc[i][j] = (f32x4){0.f, 0.f, 0.f, 0.f};

    const int srow = wave * 16 + (lane >> 2);
    const int kE = swz ? ((lane & 3) ^ ((lane >> 3) & 3)) * 8 : (lane & 3) * 8;
    const int frow = lane & 15;
    const int kk = swz ? (((lane >> 4) ^ ((lane >> 1) & 3)) & 3) * 8 : (lane >> 4) * 8;

    const int steps = K / 32;

    auto stage = [&](int buf, int t) {
        int k0 = t * 32;
        unsigned short* As = smem + buf * 12288;
        unsigned short* Bs = As + 4096;
        GLD_LDS(A + (size_t)(m0 + 0 * 64 + srow) * K + k0 + kE, &As[0 * 2048 + wave * 512]);
        GLD_LDS(A + (size_t)(m0 + 1 * 64 + srow) * K + k0 + kE, &As[1 * 2048 + wave * 512]);
        GLD_LDS(W + (size_t)(n0 + 0 * 64 + srow) * K + k0 + kE, &Bs[0 * 2048 + wave * 512]);
        GLD_LDS(W + (size_t)(n0 + 1 * 64 + srow) * K + k0 + kE, &Bs[1 * 2048 + wave * 512]);
        GLD_LDS(W + (size_t)(n0 + 2 * 64 + srow) * K + k0 + kE, &Bs[2 * 2048 + wave * 512]);
        GLD_LDS(W + (size_t)(n0 + 3 * 64 + srow) * K + k0 + kE, &Bs[3 * 2048 + wave * 512]);
    };

    stage(0, 0);
    __syncthreads();
    int cur = 0;
    for (int t = 0; t < steps; ++t) {
        if (t + 1 < steps) stage(cur ^ 1, t + 1);
        unsigned short* As = smem + cur * 12288;
        unsigned short* Bs = As + 4096;
        bf16x8 af[4], bfr[8];
#pragma unroll
        for (int u = 0; u < 4; ++u)
            af[u] = *(const bf16x8*)&As[(wm * 64 + u * 16 + frow) * 32 + kk];
#pragma unroll
        for (int u = 0; u < 8; ++u)
            bfr[u] = *(const bf16x8*)&Bs[(wn * 128 + u * 16 + frow) * 32 + kk];
#pragma unroll
        for (int i = 0; i < 4; ++i)
#pragma unroll
            for (int j = 0; j < 8; ++j)
                acc[i][j] = __builtin_amdgcn_mfma_f32_16x16x32_bf16(
                    af[i], bfr[j], acc[i][j], 0, 0, 0);
        __syncthreads();
        cur ^= 1;
    }

    if (!isQ || !q_fp32) {
        float bvj[8];
#pragma unroll
        for (int j = 0; j < 8; ++j)
            bvj[j] = isQ ? bias[n0 + wn * 128 + j * 16 + (lane & 15)] : 0.f;
        unsigned short* Cout = isQ ? (unsigned short*)Q : P;
        epilogue_bf16(acc, bvj, 0, isQ ? 0 : permM, smem, wave, lane,
                      Cout, m0, n0, wm, wn, M, N);
    } else {
        // fp32 Q: scalar stores are 64 B per quarter-wave -> already coalesced
        const int col = lane & 15;
        const int rgrp = (lane >> 4) * 4;
        float* Qf = (float*)Q;
#pragma unroll
        for (int j = 0; j < 8; ++j) {
            int n = n0 + wn * 128 + j * 16 + col;
            float bv = bias[n];
#pragma unroll
            for (int i = 0; i < 4; ++i) {
                int mBase = m0 + wm * 64 + i * 16 + rgrp;
#pragma unroll
                for (int r = 0; r < 4; ++r) {
                    int m = mBase + r;
                    if (m >= M) continue;
                    Qf[(size_t)m * N + n] = acc[i][j][r] + bv;
                }
            }
        }
    }
}

// ---------------------------------------------------------------------------
extern "C" void kernel_launch(void* const* d_in, const int* in_sizes, int n_in,
                              void* d_out, int out_size, void* d_ws, size_t ws_size,
                              hipStream_t stream) {
    const float* x   = (const float*)d_in[0];
    const int*   e   = (const int*)d_in[1];
    const float* Wl0 = (const float*)d_in[2];
    const float* bl0 = (const float*)d_in[3];
    const float* Wr0 = (const float*)d_in[4];
    const float* Wl1 = (const float*)d_in[5];
    const float* bl1 = (const float*)d_in[6];
    const float* Wr1 = (const float*)d_in[7];
    const float* Wl2 = (const float*)d_in[8];
    const float* bl2 = (const float*)d_in[9];
    const float* Wr2 = (const float*)d_in[10];
    float* out = (float*)d_out;

    const int N = in_sizes[0] / 128;           // 50000 nodes
    const int E = in_sizes[1] / 2;             // 800000 edges
    const int Mpad = ((N + 127) / 128) * 128;  // 50048: GEMM staging never OOB

    char* ws = (char*)d_ws;
    size_t off = 0;
    auto alloc = [&](size_t bytes) { size_t o = off; off = align_up(off + bytes, 512); return o; };

    size_t o_nz     = alloc(4);
    size_t o_cnt    = alloc((size_t)N * 4);
    size_t o_cursor = alloc((size_t)N * 4);
    size_t zero_end = off;                       // [0, zero_end) zeroed each call
    size_t o_part   = alloc(1024 * 4);
    size_t o_offs   = alloc((size_t)(N + 1) * 4);
    size_t o_inv    = alloc((size_t)N * 4);
    size_t o_src    = alloc((size_t)E * 4);
    size_t o_dst    = alloc((size_t)E * 4);
    size_t o_sort   = alloc((size_t)E * 4);
    size_t o_xb     = alloc((size_t)Mpad * 128 * 2);   // bf16 x row-major
    size_t o_aggx   = alloc((size_t)Mpad * 128 * 2);   // bf16 agg(x)
    size_t o_h      = alloc((size_t)Mpad * 512 * 2);   // h0, then h1
    size_t o_P      = alloc((size_t)Mpad * 512 * 2);   // P1 [2][Mpad][256], then P2 (256)
    size_t o_Q      = alloc((size_t)Mpad * 512 * 2);   // Q1 bf16 (512), then Q2 fp32 (256)
    size_t o_wl0    = alloc((size_t)512 * 128 * 2);
    size_t o_wr0    = alloc((size_t)512 * 128 * 2);
    size_t o_wl1    = alloc((size_t)512 * 512 * 2);
    size_t o_wr1    = alloc((size_t)512 * 512 * 2);
    size_t o_wl2    = alloc((size_t)256 * 512 * 2);
    size_t o_wr2    = alloc((size_t)256 * 512 * 2);
    (void)ws_size; (void)n_in; (void)out_size;

    int*            nz     = (int*)(ws + o_nz);
    int*            cnt    = (int*)(ws + o_cnt);
    int*            cursor = (int*)(ws + o_cursor);
    int*            part   = (int*)(ws + o_part);
    int*            offs   = (int*)(ws + o_offs);
    float*          inv    = (float*)(ws + o_inv);
    int*            src32  = (int*)(ws + o_src);
    int*            dst32  = (int*)(ws + o_dst);
    int*            sorted = (int*)(ws + o_sort);
    unsigned short* xb     = (unsigned short*)(ws + o_xb);
    unsigned short* aggx   = (unsigned short*)(ws + o_aggx);
    unsigned short* hbuf   = (unsigned short*)(ws + o_h);
    unsigned short* Pbuf   = (unsigned short*)(ws + o_P);
    unsigned short* Qbuf   = (unsigned short*)(ws + o_Q);   // bf16 view (layer 1)
    float*          Qf     = (float*)(ws + o_Q);            // fp32 view (layer 2)
    unsigned short* wl0b   = (unsigned short*)(ws + o_wl0);
    unsigned short* wr0b   = (unsigned short*)(ws + o_wr0);
    unsigned short* wl1b   = (unsigned short*)(ws + o_wl1);
    unsigned short* wr1b   = (unsigned short*)(ws + o_wr1);
    unsigned short* wl2b   = (unsigned short*)(ws + o_wl2);
    unsigned short* wr2b   = (unsigned short*)(ws + o_wr2);

    // zero nz/cnt/cursor (ws poisoned 0xAA before every call)
    int zn = (int)(zero_end / 4);
    zero_kernel<<<(zn + 255) / 256, 256, 0, stream>>>((int*)ws, zn);

    int eb = (E + 255) / 256;
    detect_kernel<<<1, 256, 0, stream>>>(e, nz, E);
    conv_count_kernel<<<eb, 256, 0, stream>>>(e, nz, src32, dst32, cnt, E);

    const int C = (N + 1023) / 1024;
    scan1_kernel<<<4, 256, 0, stream>>>(cnt, part, N, C);
    scan2_kernel<<<1, 1024, 0, stream>>>(part);
    scan3_kernel<<<4, 256, 0, stream>>>(cnt, part, offs, N, C, E);
    inv_kernel<<<(N + 255) / 256, 256, 0, stream>>>(cnt, inv, N);
    fill_kernel<<<eb, 256, 0, stream>>>(src32, dst32, offs, cursor, sorted, E);

    // conversions to bf16
    int n4 = N * 128 / 4;
    cvt_bf16_kernel<<<(n4 + 255) / 256, 256, 0, stream>>>(x, xb, n4);
    cvt_bf16_kernel<<<(512 * 128 / 4 + 255) / 256, 256, 0, stream>>>(Wl0, wl0b, 512 * 128 / 4);
    cvt_bf16_kernel<<<(512 * 128 / 4 + 255) / 256, 256, 0, stream>>>(Wr0, wr0b, 512 * 128 / 4);
    cvt_bf16_kernel<<<(512 * 512 / 4 + 255) / 256, 256, 0, stream>>>(Wl1, wl1b, 512 * 512 / 4);
    cvt_bf16_kernel<<<(512 * 512 / 4 + 255) / 256, 256, 0, stream>>>(Wr1, wr1b, 512 * 512 / 4);
    cvt_bf16_kernel<<<(256 * 512 / 4 + 255) / 256, 256, 0, stream>>>(Wl2, wl2b, 256 * 512 / 4);
    cvt_bf16_kernel<<<(256 * 512 / 4 + 255) / 256, 256, 0, stream>>>(Wr2, wr2b, 256 * 512 / 4);

    const int aggBlocks = (N + 3) / 4;
    const int mBlocks = Mpad / 128;

    // Layer 0: agg-then-GEMM (aggregating 128-dim x is the cheap side).
    agg128_kernel<<<aggBlocks, 256, 0, stream>>>(xb, sorted, offs, inv, aggx, N);
    sage_gemm_mfma<<<2 * mBlocks, 256, 0, stream>>>(
        aggx, xb, wl0b, wr0b, bl0, hbuf, N, 512, 128);

    // Layer 1: GEMM-then-agg: P1=h0@Wl1^T (half-split [2][Mpad][256]),
    // Q1=h0@Wr1^T+bl1 (row-major); h1 = relu(inv*sum P1[src] + Q1) in two
    // sequential half-launches. swz=0: plain contiguous staging (r11 showed
    // the 16 B-granule swizzle regressed this launch 83->100 us).
    dual_gemm_mfma<<<4 * mBlocks, 256, 0, stream>>>(
        hbuf, wl1b, wr1b, bl1, Pbuf, Qbuf, N, 512, 512, 0, Mpad, 0);
    aggfuse512h_kernel<<<aggBlocks, 256, 0, stream>>>(
        Pbuf, Qbuf, sorted, offs, inv, hbuf, N, Mpad, 0);
    aggfuse512h_kernel<<<aggBlocks, 256, 0, stream>>>(
        Pbuf, Qbuf, sorted, offs, inv, hbuf, N, Mpad, 1);

    // Layer 2: GEMM-then-agg at 256-dim (row-major P2); swz=1 (kept).
    // out = inv*sum P2[src] + Q2 (fp32, no relu)
    dual_gemm_mfma<<<2 * mBlocks, 256, 0, stream>>>(
        hbuf, wl2b, wr2b, bl2, Pbuf, (void*)Qf, N, 256, 512, 1, 0, 1);
    aggfuse256_kernel<<<aggBlocks, 256, 0, stream>>>(
        Pbuf, Qf, sorted, offs, inv, out, N);
}